// Round 2
// baseline (2021.261 us; speedup 1.0000x reference)
//
#include <hip/hip_runtime.h>
#include <math.h>

#define NN 1024
#define SS 2
#define HH 256
#define EE 32768
#define NHEAD 8
#define LL 4

// ---------------------------------------------------------------------------
// Generic fp32 GEMM: Y[M][N] = X[M][K] @ W[N][K]^T + bias (+ rowscale*bias)
// (+ resid) (relu).  Grid: (N/64, M/64), block 256.  M,N multiples of 64,
// K multiple of 16 (true for all call sites).
// ---------------------------------------------------------------------------
template<bool RELU, bool RESID, bool ROWSCALE>
__global__ __launch_bounds__(256)
void gemm_xwt(const float* __restrict__ X, int ldx,
              const float* __restrict__ W, int ldw,
              const float* __restrict__ bias,
              const float* __restrict__ resid, int ldr,
              const float* __restrict__ rowscale,
              float* __restrict__ Y, int ldy, int K)
{
    __shared__ __align__(16) float Xs[16][68];
    __shared__ __align__(16) float Ws[16][68];
    const int tid = threadIdx.x;
    const int bn0 = blockIdx.x * 64;
    const int bm0 = blockIdx.y * 64;
    const int tx = tid & 15, ty = tid >> 4;
    const int lc = tid & 15, lr = tid >> 4;
    float acc[4][4];
#pragma unroll
    for (int i = 0; i < 4; i++)
#pragma unroll
        for (int j = 0; j < 4; j++) acc[i][j] = 0.f;

    for (int k0 = 0; k0 < K; k0 += 16) {
#pragma unroll
        for (int i = 0; i < 4; i++) {
            int r = lr * 4 + i;
            Xs[lc][r] = X[(size_t)(bm0 + r) * ldx + k0 + lc];
            Ws[lc][r] = W[(size_t)(bn0 + r) * ldw + k0 + lc];
        }
        __syncthreads();
#pragma unroll
        for (int kk = 0; kk < 16; kk++) {
            float4 av = *reinterpret_cast<const float4*>(&Xs[kk][ty * 4]);
            float4 bv = *reinterpret_cast<const float4*>(&Ws[kk][tx * 4]);
            float a4[4] = {av.x, av.y, av.z, av.w};
            float b4[4] = {bv.x, bv.y, bv.z, bv.w};
#pragma unroll
            for (int i = 0; i < 4; i++)
#pragma unroll
                for (int j = 0; j < 4; j++)
                    acc[i][j] = fmaf(a4[i], b4[j], acc[i][j]);
        }
        __syncthreads();
    }
#pragma unroll
    for (int i = 0; i < 4; i++) {
        int m = bm0 + ty * 4 + i;
        float rs = ROWSCALE ? rowscale[m] : 1.f;
        float* yp = Y + (size_t)m * ldy + bn0 + tx * 4;
        const float* rp = RESID ? (resid + (size_t)m * ldr + bn0 + tx * 4) : nullptr;
#pragma unroll
        for (int j = 0; j < 4; j++) {
            float b = bias[bn0 + tx * 4 + j];
            float v = acc[i][j] + (ROWSCALE ? rs * b : b);
            if (RESID) v += rp[j];
            if (RELU) v = fmaxf(v, 0.f);
            yp[j] = v;
        }
    }
}

// ---------------------------------------------------------------------------
// LayerNorm over rows of length 256.  One block (256 thr) per row.
// Y = ln(X)*g + b (+ resid)
// ---------------------------------------------------------------------------
template<bool RESID>
__global__ __launch_bounds__(256)
void ln_kernel(const float* __restrict__ X, const float* __restrict__ g,
               const float* __restrict__ b, const float* __restrict__ resid,
               float* __restrict__ Y)
{
    int row = blockIdx.x, t = threadIdx.x;
    float v = X[(size_t)row * HH + t];
    float s1 = v, s2 = v * v;
#pragma unroll
    for (int m = 32; m >= 1; m >>= 1) {
        s1 += __shfl_xor(s1, m);
        s2 += __shfl_xor(s2, m);
    }
    __shared__ float w1[4], w2[4];
    if ((t & 63) == 0) { w1[t >> 6] = s1; w2[t >> 6] = s2; }
    __syncthreads();
    float tot1 = w1[0] + w1[1] + w1[2] + w1[3];
    float tot2 = w2[0] + w2[1] + w2[2] + w2[3];
    float mean = tot1 * (1.f / HH);
    float var = tot2 * (1.f / HH) - mean * mean;
    float inv = rsqrtf(var + 1e-5f);
    float out = (v - mean) * inv * g[t] + b[t];
    if (RESID) out += resid[(size_t)row * HH + t];
    Y[(size_t)row * HH + t] = out;
}

// ---------------------------------------------------------------------------
// Flash attention over N=1024 tokens, d=32, fp32.
// Grid (16 q-tiles of 64, NHEAD, SS), block 256 = 64 queries x 4 key-lanes.
// qkv layout [s][n][768] (q:0..255, k:256..511, v:512..767).
// out layout [s][n][256] (heads merged).
// ---------------------------------------------------------------------------
__global__ __launch_bounds__(256)
void attn_graph_kernel(const float* __restrict__ qkv, float* __restrict__ out)
{
    const int s = blockIdx.z, hh = blockIdx.y, qt = blockIdx.x;
    const int tid = threadIdx.x;
    const int qi = tid >> 2, sub = tid & 3;
    __shared__ __align__(16) float Qs[64][36];
    __shared__ __align__(16) float Ks[128][36];
    __shared__ __align__(16) float Vs[128][36];
    const float* base = qkv + (size_t)s * NN * 768;
    {
        int r = tid >> 2, c0 = (tid & 3) * 8;
        const float* src = base + (size_t)(qt * 64 + r) * 768 + hh * 32 + c0;
        *reinterpret_cast<float4*>(&Qs[r][c0])     = *reinterpret_cast<const float4*>(src);
        *reinterpret_cast<float4*>(&Qs[r][c0 + 4]) = *reinterpret_cast<const float4*>(src + 4);
    }
    __syncthreads();
    float q[32];
#pragma unroll
    for (int c = 0; c < 32; c++) q[c] = Qs[qi][c];
    float mrun = -INFINITY, lrun = 0.f;
    float o[32];
#pragma unroll
    for (int c = 0; c < 32; c++) o[c] = 0.f;
    const float scale = 0.17677669529663687f; // 1/sqrt(32)

    for (int kc = 0; kc < NN; kc += 128) {
        __syncthreads();
        {
            int r = tid >> 1, c0 = (tid & 1) * 16;
            const float* ksrc = base + (size_t)(kc + r) * 768 + 256 + hh * 32 + c0;
            const float* vsrc = ksrc + 256;
#pragma unroll
            for (int u = 0; u < 4; u++) {
                *reinterpret_cast<float4*>(&Ks[r][c0 + 4 * u]) = *reinterpret_cast<const float4*>(ksrc + 4 * u);
                *reinterpret_cast<float4*>(&Vs[r][c0 + 4 * u]) = *reinterpret_cast<const float4*>(vsrc + 4 * u);
            }
        }
        __syncthreads();
        float sc[32];
#pragma unroll
        for (int i = 0; i < 32; i++) {
            int j = sub + 4 * i;
            float d = 0.f;
#pragma unroll
            for (int c = 0; c < 32; c++) d = fmaf(q[c], Ks[j][c], d);
            sc[i] = d * scale;
        }
        float cm = sc[0];
#pragma unroll
        for (int i = 1; i < 32; i++) cm = fmaxf(cm, sc[i]);
        float mn = fmaxf(mrun, cm);
        float corr = __expf(mrun - mn);
        lrun *= corr;
#pragma unroll
        for (int c = 0; c < 32; c++) o[c] *= corr;
#pragma unroll
        for (int i = 0; i < 32; i++) {
            int j = sub + 4 * i;
            float p = __expf(sc[i] - mn);
            lrun += p;
#pragma unroll
            for (int c = 0; c < 32; c++) o[c] = fmaf(p, Vs[j][c], o[c]);
        }
        mrun = mn;
    }
    // merge the 4 key-lanes of each query (lanes qi*4+{0..3}, same wave)
#pragma unroll
    for (int mask = 1; mask <= 2; mask <<= 1) {
        float m2 = __shfl_xor(mrun, mask);
        float l2 = __shfl_xor(lrun, mask);
        float mn = fmaxf(mrun, m2);
        float c1 = __expf(mrun - mn), c2 = __expf(m2 - mn);
        lrun = lrun * c1 + l2 * c2;
#pragma unroll
        for (int c = 0; c < 32; c++) {
            float oc = o[c];
            float op = __shfl_xor(oc, mask);
            o[c] = oc * c1 + op * c2;
        }
        mrun = mn;
    }
    float invl = 1.f / lrun;
    float* dst = out + ((size_t)s * NN + qt * 64 + qi) * HH + hh * 32;
    // all 4 lanes hold the full o[32]; lane `sub` writes its 8 channels.
    // static indices only (avoid scratch spill from runtime-indexed regs).
#pragma unroll
    for (int c = 0; c < 32; c++) {
        if ((c >> 3) == sub) dst[c] = o[c] * invl;
    }
}

// ---------------------------------------------------------------------------
// Tiny T=2 attention for the transformer phase. One thread per (n, head).
// qkvt layout [n][s][768], out [n][s][256].
// ---------------------------------------------------------------------------
__global__ __launch_bounds__(256)
void attn_t2_kernel(const float* __restrict__ qkvt, float* __restrict__ out)
{
    int idx = blockIdx.x * 256 + threadIdx.x;
    int n = idx >> 3, hh = idx & 7;
    const float* p0 = qkvt + ((size_t)n * SS + 0) * 768 + hh * 32;
    const float* p1 = qkvt + ((size_t)n * SS + 1) * 768 + hh * 32;
    float s00 = 0, s01 = 0, s10 = 0, s11 = 0;
#pragma unroll
    for (int c4 = 0; c4 < 8; c4++) {
        float4 q0 = *reinterpret_cast<const float4*>(p0 + c4 * 4);
        float4 q1 = *reinterpret_cast<const float4*>(p1 + c4 * 4);
        float4 k0 = *reinterpret_cast<const float4*>(p0 + 256 + c4 * 4);
        float4 k1 = *reinterpret_cast<const float4*>(p1 + 256 + c4 * 4);
        s00 += q0.x * k0.x + q0.y * k0.y + q0.z * k0.z + q0.w * k0.w;
        s01 += q0.x * k1.x + q0.y * k1.y + q0.z * k1.z + q0.w * k1.w;
        s10 += q1.x * k0.x + q1.y * k0.y + q1.z * k0.z + q1.w * k0.w;
        s11 += q1.x * k1.x + q1.y * k1.y + q1.z * k1.z + q1.w * k1.w;
    }
    const float scale = 0.17677669529663687f;
    s00 *= scale; s01 *= scale; s10 *= scale; s11 *= scale;
    float m0 = fmaxf(s00, s01), m1 = fmaxf(s10, s11);
    float p00 = __expf(s00 - m0), p01 = __expf(s01 - m0);
    float p10 = __expf(s10 - m1), p11 = __expf(s11 - m1);
    float i0 = 1.f / (p00 + p01), i1 = 1.f / (p10 + p11);
    p00 *= i0; p01 *= i0; p10 *= i1; p11 *= i1;
    float* o0 = out + ((size_t)n * SS + 0) * HH + hh * 32;
    float* o1 = out + ((size_t)n * SS + 1) * HH + hh * 32;
#pragma unroll
    for (int c4 = 0; c4 < 8; c4++) {
        float4 v0 = *reinterpret_cast<const float4*>(p0 + 512 + c4 * 4);
        float4 v1 = *reinterpret_cast<const float4*>(p1 + 512 + c4 * 4);
        float4 r0, r1;
        r0.x = p00 * v0.x + p01 * v1.x; r0.y = p00 * v0.y + p01 * v1.y;
        r0.z = p00 * v0.z + p01 * v1.z; r0.w = p00 * v0.w + p01 * v1.w;
        r1.x = p10 * v0.x + p11 * v1.x; r1.y = p10 * v0.y + p11 * v1.y;
        r1.z = p10 * v0.z + p11 * v1.z; r1.w = p10 * v0.w + p11 * v1.w;
        *reinterpret_cast<float4*>(o0 + c4 * 4) = r0;
        *reinterpret_cast<float4*>(o1 + c4 * 4) = r1;
    }
}

// ---------------------------------------------------------------------------
// Edge aggregation: Rn[s][n][:] = (sum over edges e with row[e]==n of
//   relu(P[s][col[e]][:] + ea[s][e]·W1b)) / cnt[n]
// P already includes bias b1. Grid (NN, SS), block 256 (one channel/thread).
// ---------------------------------------------------------------------------
__global__ __launch_bounds__(256)
void edge_agg_kernel(const float* __restrict__ P, const float* __restrict__ ea,
                     const float* __restrict__ W1, // layer base, rows of 259
                     const int* __restrict__ off, const int* __restrict__ eid,
                     const int* __restrict__ colIdx, const float* __restrict__ cnt,
                     float* __restrict__ Rn)
{
    const int n = blockIdx.x, s = blockIdx.y;
    const int t = threadIdx.x;
    const float w0 = W1[(size_t)t * 259 + 256];
    const float w1 = W1[(size_t)t * 259 + 257];
    const float w2 = W1[(size_t)t * 259 + 258];
    float acc = 0.f;
    const int beg = off[n], end = off[n + 1];
    const float* eab = ea + (size_t)s * EE * 3;
    const float* Pb = P + (size_t)s * NN * HH;
    for (int p = beg; p < end; ++p) {
        int e = eid[p];
        int c = colIdx[e];
        float e0 = eab[(size_t)e * 3 + 0];
        float e1 = eab[(size_t)e * 3 + 1];
        float e2 = eab[(size_t)e * 3 + 2];
        float u = Pb[(size_t)c * HH + t] + e0 * w0 + e1 * w1 + e2 * w2;
        acc += fmaxf(u, 0.f);
    }
    Rn[((size_t)s * NN + n) * HH + t] = acc / cnt[n];
}

// --------------------------- small helper kernels --------------------------
__global__ __launch_bounds__(256)
void enc1_kernel(const float* __restrict__ x, const float* __restrict__ w1,
                 const float* __restrict__ b1, float* __restrict__ t0)
{
    int m = blockIdx.x, j = threadIdx.x;
    float x0 = x[(size_t)m * 3 + 0], x1 = x[(size_t)m * 3 + 1], x2 = x[(size_t)m * 3 + 2];
    float v = fmaf(x0, w1[j * 3 + 0], fmaf(x1, w1[j * 3 + 1], fmaf(x2, w1[j * 3 + 2], b1[j])));
    t0[(size_t)m * HH + j] = fmaxf(v, 0.f);
}

__global__ __launch_bounds__(256)
void deg_kernel(const int* __restrict__ rowIdx, int* __restrict__ deg)
{
    int e = blockIdx.x * 256 + threadIdx.x;
    atomicAdd(&deg[rowIdx[e]], 1);
}

__global__ __launch_bounds__(256)
void cnt_kernel(const int* __restrict__ deg, float* __restrict__ cnt,
                float* __restrict__ bscale)
{
    int n = blockIdx.x * 256 + threadIdx.x;
    int d = deg[n];
    cnt[n] = d > 0 ? (float)d : 1.f;
    float bs = d > 0 ? 1.f : 0.f;
    bscale[n] = bs;
    bscale[NN + n] = bs;
}

__global__ void scan1024(const int* __restrict__ deg, int* __restrict__ off)
{
    __shared__ int tmp[1024];
    int t = threadIdx.x;
    tmp[t] = deg[t];
    __syncthreads();
    for (int d = 1; d < 1024; d <<= 1) {
        int v = 0;
        if (t >= d) v = tmp[t - d];
        __syncthreads();
        if (t >= d) tmp[t] += v;
        __syncthreads();
    }
    off[t + 1] = tmp[t];
    if (t == 0) off[0] = 0;
}

__global__ __launch_bounds__(256)
void csr_scatter(const int* __restrict__ rowIdx, int* __restrict__ cursor,
                 int* __restrict__ eidb)
{
    int e = blockIdx.x * 256 + threadIdx.x;
    int p = atomicAdd(&cursor[rowIdx[e]], 1);
    eidb[p] = e;
}

__global__ __launch_bounds__(256)
void ea_kernel(const float* __restrict__ h, const int* __restrict__ rowIdx,
               const int* __restrict__ colIdx, float* __restrict__ ea)
{
    int idx = blockIdx.x * 256 + threadIdx.x; // [0, SS*EE)
    int e = idx & (EE - 1);
    int s = idx >> 15;
    int r = rowIdx[e], c = colIdx[e];
    const float* hb = h + (size_t)s * NN * HH;
    float* o = ea + (size_t)idx * 3;
    o[0] = hb[(size_t)c * HH + 0] - hb[(size_t)r * HH + 0];
    o[1] = hb[(size_t)c * HH + 1] - hb[(size_t)r * HH + 1];
    o[2] = hb[(size_t)c * HH + 2] - hb[(size_t)r * HH + 2];
}

__global__ __launch_bounds__(256)
void transpose_sn(const float* __restrict__ h, float* __restrict__ ht)
{
    int c = threadIdx.x, n = blockIdx.x, s = blockIdx.y;
    ht[((size_t)n * SS + s) * HH + c] = h[((size_t)s * NN + n) * HH + c];
}

__global__ __launch_bounds__(64)
void final_kernel(const float* __restrict__ o1, const float* __restrict__ w2,
                  const float* __restrict__ b2, float* __restrict__ out)
{
    int n = blockIdx.x, t = threadIdx.x;
    float a0 = 0, a1 = 0, a2 = 0;
#pragma unroll
    for (int r = 0; r < 4; r++) {
        float v = o1[(size_t)n * HH + t + 64 * r];
        a0 = fmaf(v, w2[0 * HH + t + 64 * r], a0);
        a1 = fmaf(v, w2[1 * HH + t + 64 * r], a1);
        a2 = fmaf(v, w2[2 * HH + t + 64 * r], a2);
    }
#pragma unroll
    for (int m = 32; m >= 1; m >>= 1) {
        a0 += __shfl_xor(a0, m);
        a1 += __shfl_xor(a1, m);
        a2 += __shfl_xor(a2, m);
    }
    if (t == 0) {
        out[(size_t)n * 3 + 0] = a0 + b2[0];
        out[(size_t)n * 3 + 1] = a1 + b2[1];
        out[(size_t)n * 3 + 2] = a2 + b2[2];
    }
}

// ---------------------------------------------------------------------------
extern "C" void kernel_launch(void* const* d_in, const int* in_sizes, int n_in,
                              void* d_out, int out_size, void* d_ws, size_t ws_size,
                              hipStream_t stream)
{
    const float* x      = (const float*)d_in[0];
    const int*   eidx   = (const int*)d_in[1];
    const float* fe_w1  = (const float*)d_in[2];
    const float* fe_b1  = (const float*)d_in[3];
    const float* fe_w2  = (const float*)d_in[4];
    const float* fe_b2  = (const float*)d_in[5];
    const float* g_inw  = (const float*)d_in[6];
    const float* g_inb  = (const float*)d_in[7];
    const float* g_outw = (const float*)d_in[8];
    const float* g_outb = (const float*)d_in[9];
    const float* g_m1w  = (const float*)d_in[10];
    const float* g_m1b  = (const float*)d_in[11];
    const float* g_m2w  = (const float*)d_in[12];
    const float* g_m2b  = (const float*)d_in[13];
    const float* g_n1g  = (const float*)d_in[14];
    const float* g_n1b  = (const float*)d_in[15];
    const float* g_n2g  = (const float*)d_in[16];
    const float* g_n2b  = (const float*)d_in[17];
    const float* t_inw  = (const float*)d_in[18];
    const float* t_inb  = (const float*)d_in[19];
    const float* t_outw = (const float*)d_in[20];
    const float* t_outb = (const float*)d_in[21];
    const float* t_l1w  = (const float*)d_in[22];
    const float* t_l1b  = (const float*)d_in[23];
    const float* t_l2w  = (const float*)d_in[24];
    const float* t_l2b  = (const float*)d_in[25];
    const float* t_n1g  = (const float*)d_in[26];
    const float* t_n1b  = (const float*)d_in[27];
    const float* t_n2g  = (const float*)d_in[28];
    const float* t_n2b  = (const float*)d_in[29];
    const float* o_w1   = (const float*)d_in[30];
    const float* o_b1   = (const float*)d_in[31];
    const float* o_w2   = (const float*)d_in[32];
    const float* o_b2   = (const float*)d_in[33];

    const int* rowIdx = eidx;
    const int* colIdx = eidx + EE;

    float* w = (float*)d_ws;
    const size_t F = (size_t)SS * NN * HH; // 524288 floats
    float* h      = w;
    float* hn     = w + F;        // also ht in transformer phase
    float* qkv    = w + 2 * F;    // 3F; also t0 and qkvt
    float* attno  = w + 5 * F;
    float* a      = w + 6 * F;
    float* P      = w + 7 * F;    // also tmp in transformer phase
    float* Rn     = w + 8 * F;
    float* aggn   = w + 9 * F;
    float* ffh    = w + 10 * F;   // 4F
    float* ea     = w + 14 * F;                  // SS*EE*3
    float* o1     = ea + (size_t)SS * EE * 3;    // NN*HH
    float* cnt    = o1 + (size_t)NN * HH;        // NN
    float* bscale = cnt + NN;                    // 2*NN
    int* ib       = (int*)(bscale + 2 * NN);
    int* deg      = ib;                  // NN
    int* off      = ib + NN;             // NN+1
    int* cursor   = ib + 2 * NN + 1;     // NN
    int* eidbuf   = ib + 3 * NN + 1;     // EE

    dim3 b256(256);

    // ---- feature encoder ----
    float* t0 = qkv;
    enc1_kernel<<<dim3(SS * NN), b256, 0, stream>>>(x, fe_w1, fe_b1, t0);
    gemm_xwt<false, false, false><<<dim3(4, 32), b256, 0, stream>>>(
        t0, HH, fe_w2, HH, fe_b2, nullptr, 0, nullptr, h, HH, HH);

    // ---- graph prep: degrees, CSR, edge attrs ----
    hipMemsetAsync(deg, 0, NN * sizeof(int), stream);
    deg_kernel<<<dim3(EE / 256), b256, 0, stream>>>(rowIdx, deg);
    cnt_kernel<<<dim3(NN / 256), b256, 0, stream>>>(deg, cnt, bscale);
    scan1024<<<dim3(1), dim3(1024), 0, stream>>>(deg, off);
    hipMemcpyAsync(cursor, off, NN * sizeof(int), hipMemcpyDeviceToDevice, stream);
    csr_scatter<<<dim3(EE / 256), b256, 0, stream>>>(rowIdx, cursor, eidbuf);
    ea_kernel<<<dim3(SS * EE / 256), b256, 0, stream>>>(h, rowIdx, colIdx, ea);

    // ---- graph attention + message-passing layers ----
    for (int l = 0; l < LL; l++) {
        ln_kernel<false><<<dim3(SS * NN), b256, 0, stream>>>(
            h, g_n1g + l * HH, g_n1b + l * HH, nullptr, hn);
        gemm_xwt<false, false, false><<<dim3(12, 32), b256, 0, stream>>>(
            hn, HH, g_inw + (size_t)l * 3 * HH * HH, HH, g_inb + l * 3 * HH,
            nullptr, 0, nullptr, qkv, 3 * HH, HH);
        attn_graph_kernel<<<dim3(16, NHEAD, SS), b256, 0, stream>>>(qkv, attno);
        gemm_xwt<false, true, false><<<dim3(4, 32), b256, 0, stream>>>(
            attno, HH, g_outw + (size_t)l * HH * HH, HH, g_outb + l * HH,
            h, HH, nullptr, a, HH, HH);
        // P = a @ W1a^T + b1   (W1 rows are length 259: 256 for a, 3 for ea)
        gemm_xwt<false, false, false><<<dim3(4, 32), b256, 0, stream>>>(
            a, HH, g_m1w + (size_t)l * HH * 259, 259, g_m1b + l * HH,
            nullptr, 0, nullptr, P, HH, HH);
        edge_agg_kernel<<<dim3(NN, SS), b256, 0, stream>>>(
            P, ea, g_m1w + (size_t)l * HH * 259, off, eidbuf, colIdx, cnt, Rn);
        gemm_xwt<false, false, true><<<dim3(4, 32), b256, 0, stream>>>(
            Rn, HH, g_m2w + (size_t)l * HH * HH, HH, g_m2b + l * HH,
            nullptr, 0, bscale, aggn, HH, HH);
        ln_kernel<true><<<dim3(SS * NN), b256, 0, stream>>>(
            aggn, g_n2g + l * HH, g_n2b + l * HH, h, h);
    }

    // ---- transpose to [n][s][H] ----
    float* ht = hn;
    transpose_sn<<<dim3(NN, SS), b256, 0, stream>>>(h, ht);

    // ---- transformer layers over T=S=2 ----
    float* tmp = P;
    for (int l = 0; l < LL; l++) {
        gemm_xwt<false, false, false><<<dim3(12, 32), b256, 0, stream>>>(
            ht, HH, t_inw + (size_t)l * 3 * HH * HH, HH, t_inb + l * 3 * HH,
            nullptr, 0, nullptr, qkv, 3 * HH, HH);
        attn_t2_kernel<<<dim3(NN * NHEAD / 256), b256, 0, stream>>>(qkv, attno);
        gemm_xwt<false, true, false><<<dim3(4, 32), b256, 0, stream>>>(
            attno, HH, t_outw + (size_t)l * HH * HH, HH, t_outb + l * HH,
            ht, HH, nullptr, tmp, HH, HH);
        ln_kernel<false><<<dim3(SS * NN), b256, 0, stream>>>(
            tmp, t_n1g + l * HH, t_n1b + l * HH, nullptr, ht);
        gemm_xwt<true, false, false><<<dim3(16, 32), b256, 0, stream>>>(
            ht, HH, t_l1w + (size_t)l * 4 * HH * HH, HH, t_l1b + l * 4 * HH,
            nullptr, 0, nullptr, ffh, 4 * HH, HH);
        gemm_xwt<false, true, false><<<dim3(4, 32), b256, 0, stream>>>(
            ffh, 4 * HH, t_l2w + (size_t)l * HH * 4 * HH, 4 * HH, t_l2b + l * HH,
            ht, HH, nullptr, tmp, HH, 4 * HH);
        ln_kernel<false><<<dim3(SS * NN), b256, 0, stream>>>(
            tmp, t_n2g + l * HH, t_n2b + l * HH, nullptr, ht);
    }

    // ---- output head: last = ht[:, s=1, :] ----
    gemm_xwt<true, false, false><<<dim3(4, 16), b256, 0, stream>>>(
        ht + HH, 2 * HH, o_w1, HH, o_b1, nullptr, 0, nullptr, o1, HH, HH);
    final_kernel<<<dim3(NN), dim3(64), 0, stream>>>(o1, o_w2, o_b2, (float*)d_out);
}

// Round 3
// 1241.342 us; speedup vs baseline: 1.6283x; 1.6283x over previous
//
#include <hip/hip_runtime.h>
#include <math.h>

#define NN 1024
#define SS 2
#define HH 256
#define EE 32768
#define NHEAD 8
#define LL 4

// ---------------------------------------------------------------------------
// Generic fp32 GEMM: Y[M][N] = X[M][K] @ W[N][K]^T + bias (+ rowscale*bias)
// (+ resid) (relu).  Tile 64(M) x 32(N), block 256 = 8 tx * 32 ty, each
// thread 2 rows x 4 cols.  Grid: (N/32, M/64).  K multiple of 16.
// ---------------------------------------------------------------------------
template<bool RELU, bool RESID, bool ROWSCALE>
__global__ __launch_bounds__(256)
void gemm_xwt32(const float* __restrict__ X, int ldx,
                const float* __restrict__ W, int ldw,
                const float* __restrict__ bias,
                const float* __restrict__ resid, int ldr,
                const float* __restrict__ rowscale,
                float* __restrict__ Y, int ldy, int K)
{
    __shared__ __align__(16) float Xs[16][68];
    __shared__ __align__(16) float Ws[16][36];
    const int tid = threadIdx.x;
    const int bn0 = blockIdx.x * 32;
    const int bm0 = blockIdx.y * 64;
    const int tx = tid & 7, ty = tid >> 3;       // 8 x 32
    const int lc = tid & 15, lr = tid >> 4;      // 16 x 16 (staging)
    float acc[2][4];
#pragma unroll
    for (int i = 0; i < 2; i++)
#pragma unroll
        for (int j = 0; j < 4; j++) acc[i][j] = 0.f;

    for (int k0 = 0; k0 < K; k0 += 16) {
#pragma unroll
        for (int i = 0; i < 4; i++) {
            int r = lr * 4 + i;
            Xs[lc][r] = X[(size_t)(bm0 + r) * ldx + k0 + lc];
        }
#pragma unroll
        for (int i = 0; i < 2; i++) {
            int r = lr * 2 + i;
            Ws[lc][r] = W[(size_t)(bn0 + r) * ldw + k0 + lc];
        }
        __syncthreads();
#pragma unroll
        for (int kk = 0; kk < 16; kk++) {
            float2 av = *reinterpret_cast<const float2*>(&Xs[kk][ty * 2]);
            float4 bv = *reinterpret_cast<const float4*>(&Ws[kk][tx * 4]);
            float a2[2] = {av.x, av.y};
            float b4[4] = {bv.x, bv.y, bv.z, bv.w};
#pragma unroll
            for (int i = 0; i < 2; i++)
#pragma unroll
                for (int j = 0; j < 4; j++)
                    acc[i][j] = fmaf(a2[i], b4[j], acc[i][j]);
        }
        __syncthreads();
    }
#pragma unroll
    for (int i = 0; i < 2; i++) {
        int m = bm0 + ty * 2 + i;
        float rs = ROWSCALE ? rowscale[m] : 1.f;
        float* yp = Y + (size_t)m * ldy + bn0 + tx * 4;
        const float* rp = RESID ? (resid + (size_t)m * ldr + bn0 + tx * 4) : nullptr;
#pragma unroll
        for (int j = 0; j < 4; j++) {
            float b = bias[bn0 + tx * 4 + j];
            float v = acc[i][j] + (ROWSCALE ? rs * b : b);
            if (RESID) v += rp[j];
            if (RELU) v = fmaxf(v, 0.f);
            yp[j] = v;
        }
    }
}

// ---------------------------------------------------------------------------
// LayerNorm over rows of length 256.  One block (256 thr) per row.
// ---------------------------------------------------------------------------
template<bool RESID>
__global__ __launch_bounds__(256)
void ln_kernel(const float* __restrict__ X, const float* __restrict__ g,
               const float* __restrict__ b, const float* __restrict__ resid,
               float* __restrict__ Y)
{
    int row = blockIdx.x, t = threadIdx.x;
    float v = X[(size_t)row * HH + t];
    float s1 = v, s2 = v * v;
#pragma unroll
    for (int m = 32; m >= 1; m >>= 1) {
        s1 += __shfl_xor(s1, m);
        s2 += __shfl_xor(s2, m);
    }
    __shared__ float w1[4], w2[4];
    if ((t & 63) == 0) { w1[t >> 6] = s1; w2[t >> 6] = s2; }
    __syncthreads();
    float tot1 = w1[0] + w1[1] + w1[2] + w1[3];
    float tot2 = w2[0] + w2[1] + w2[2] + w2[3];
    float mean = tot1 * (1.f / HH);
    float var = tot2 * (1.f / HH) - mean * mean;
    float inv = rsqrtf(var + 1e-5f);
    float out = (v - mean) * inv * g[t] + b[t];
    if (RESID) out += resid[(size_t)row * HH + t];
    Y[(size_t)row * HH + t] = out;
}

// ---------------------------------------------------------------------------
// Flash attention v2: N=1024, d=32, fp32.
// Grid (32 q-tiles of 32, NHEAD, SS) = 512 blocks (2/CU).
// Block 256 = 16 q-slots x 16 key-lanes; each thread owns 2 queries
// (register-blocked) so every K/V LDS row read feeds 2 queries.
// ---------------------------------------------------------------------------
__global__ __launch_bounds__(256, 2)
void attn_graph_kernel(const float* __restrict__ qkv, float* __restrict__ out)
{
    const int s = blockIdx.z, hh = blockIdx.y, qt = blockIdx.x;
    const int tid = threadIdx.x;
    const int qslot = tid >> 4, sub = tid & 15;
    __shared__ __align__(16) float Qs[32][36];
    __shared__ __align__(16) float Ks[128][36];
    __shared__ __align__(16) float Vs[128][36];
    const float* base = qkv + (size_t)s * NN * 768;
    {
        int r = tid >> 3, c0 = (tid & 7) * 4;
        const float* src = base + (size_t)(qt * 32 + r) * 768 + hh * 32 + c0;
        *reinterpret_cast<float4*>(&Qs[r][c0]) = *reinterpret_cast<const float4*>(src);
    }
    __syncthreads();
    float qa[32], qb[32], oa[32], ob[32];
#pragma unroll
    for (int c = 0; c < 32; c++) {
        qa[c] = Qs[qslot * 2][c];
        qb[c] = Qs[qslot * 2 + 1][c];
        oa[c] = 0.f; ob[c] = 0.f;
    }
    float ma = -INFINITY, la = 0.f;
    float mb = -INFINITY, lb = 0.f;
    const float scale = 0.17677669529663687f; // 1/sqrt(32)

    for (int kc = 0; kc < NN; kc += 128) {
        __syncthreads();
        {
            int r0 = tid >> 3, c0 = (tid & 7) * 4;
#pragma unroll
            for (int u = 0; u < 4; u++) {
                int r = r0 + 32 * u;
                const float* ksrc = base + (size_t)(kc + r) * 768 + 256 + hh * 32 + c0;
                *reinterpret_cast<float4*>(&Ks[r][c0]) = *reinterpret_cast<const float4*>(ksrc);
                *reinterpret_cast<float4*>(&Vs[r][c0]) = *reinterpret_cast<const float4*>(ksrc + 256);
            }
        }
        __syncthreads();
        float sa[8], sb[8];
#pragma unroll
        for (int i = 0; i < 8; i++) {
            int j = sub + 16 * i;
            float da = 0.f, db = 0.f;
#pragma unroll
            for (int c = 0; c < 32; c++) {
                float kv = Ks[j][c];
                da = fmaf(qa[c], kv, da);
                db = fmaf(qb[c], kv, db);
            }
            sa[i] = da * scale;
            sb[i] = db * scale;
        }
        float cma = sa[0], cmb = sb[0];
#pragma unroll
        for (int i = 1; i < 8; i++) { cma = fmaxf(cma, sa[i]); cmb = fmaxf(cmb, sb[i]); }
        float mna = fmaxf(ma, cma), mnb = fmaxf(mb, cmb);
        float ca = __expf(ma - mna), cb = __expf(mb - mnb);
        la *= ca; lb *= cb;
#pragma unroll
        for (int c = 0; c < 32; c++) { oa[c] *= ca; ob[c] *= cb; }
#pragma unroll
        for (int i = 0; i < 8; i++) {
            int j = sub + 16 * i;
            float pa = __expf(sa[i] - mna);
            float pb = __expf(sb[i] - mnb);
            la += pa; lb += pb;
#pragma unroll
            for (int c = 0; c < 32; c++) {
                float vv = Vs[j][c];
                oa[c] = fmaf(pa, vv, oa[c]);
                ob[c] = fmaf(pb, vv, ob[c]);
            }
        }
        ma = mna; mb = mnb;
    }
    // merge the 16 key-lanes of each q-slot (lane bits 0..3, within wave)
#pragma unroll
    for (int mask = 1; mask <= 8; mask <<= 1) {
        float m2a = __shfl_xor(ma, mask), l2a = __shfl_xor(la, mask);
        float mna = fmaxf(ma, m2a);
        float c1a = __expf(ma - mna), c2a = __expf(m2a - mna);
        la = la * c1a + l2a * c2a;
        float m2b = __shfl_xor(mb, mask), l2b = __shfl_xor(lb, mask);
        float mnb = fmaxf(mb, m2b);
        float c1b = __expf(mb - mnb), c2b = __expf(m2b - mnb);
        lb = lb * c1b + l2b * c2b;
#pragma unroll
        for (int c = 0; c < 32; c++) {
            float ta = __shfl_xor(oa[c], mask);
            oa[c] = oa[c] * c1a + ta * c2a;
            float tb = __shfl_xor(ob[c], mask);
            ob[c] = ob[c] * c1b + tb * c2b;
        }
        ma = mna; mb = mnb;
    }
    float ia = 1.f / la, ib = 1.f / lb;
    float* dA = out + ((size_t)s * NN + qt * 32 + qslot * 2) * HH + hh * 32;
    float* dB = dA + HH;
    // lane `sub` writes channels {2*sub, 2*sub+1}; static indices only.
#pragma unroll
    for (int c2 = 0; c2 < 16; c2++) {
        if (c2 == sub) {
            *reinterpret_cast<float2*>(dA + c2 * 2) =
                make_float2(oa[c2 * 2] * ia, oa[c2 * 2 + 1] * ia);
            *reinterpret_cast<float2*>(dB + c2 * 2) =
                make_float2(ob[c2 * 2] * ib, ob[c2 * 2 + 1] * ib);
        }
    }
}

// ---------------------------------------------------------------------------
// Tiny T=2 attention for the transformer phase. One thread per (n, head).
// ---------------------------------------------------------------------------
__global__ __launch_bounds__(256)
void attn_t2_kernel(const float* __restrict__ qkvt, float* __restrict__ out)
{
    int idx = blockIdx.x * 256 + threadIdx.x;
    int n = idx >> 3, hh = idx & 7;
    const float* p0 = qkvt + ((size_t)n * SS + 0) * 768 + hh * 32;
    const float* p1 = qkvt + ((size_t)n * SS + 1) * 768 + hh * 32;
    float s00 = 0, s01 = 0, s10 = 0, s11 = 0;
#pragma unroll
    for (int c4 = 0; c4 < 8; c4++) {
        float4 q0 = *reinterpret_cast<const float4*>(p0 + c4 * 4);
        float4 q1 = *reinterpret_cast<const float4*>(p1 + c4 * 4);
        float4 k0 = *reinterpret_cast<const float4*>(p0 + 256 + c4 * 4);
        float4 k1 = *reinterpret_cast<const float4*>(p1 + 256 + c4 * 4);
        s00 += q0.x * k0.x + q0.y * k0.y + q0.z * k0.z + q0.w * k0.w;
        s01 += q0.x * k1.x + q0.y * k1.y + q0.z * k1.z + q0.w * k1.w;
        s10 += q1.x * k0.x + q1.y * k0.y + q1.z * k0.z + q1.w * k0.w;
        s11 += q1.x * k1.x + q1.y * k1.y + q1.z * k1.z + q1.w * k1.w;
    }
    const float scale = 0.17677669529663687f;
    s00 *= scale; s01 *= scale; s10 *= scale; s11 *= scale;
    float m0 = fmaxf(s00, s01), m1 = fmaxf(s10, s11);
    float p00 = __expf(s00 - m0), p01 = __expf(s01 - m0);
    float p10 = __expf(s10 - m1), p11 = __expf(s11 - m1);
    float i0 = 1.f / (p00 + p01), i1 = 1.f / (p10 + p11);
    p00 *= i0; p01 *= i0; p10 *= i1; p11 *= i1;
    float* o0 = out + ((size_t)n * SS + 0) * HH + hh * 32;
    float* o1 = out + ((size_t)n * SS + 1) * HH + hh * 32;
#pragma unroll
    for (int c4 = 0; c4 < 8; c4++) {
        float4 v0 = *reinterpret_cast<const float4*>(p0 + 512 + c4 * 4);
        float4 v1 = *reinterpret_cast<const float4*>(p1 + 512 + c4 * 4);
        float4 r0, r1;
        r0.x = p00 * v0.x + p01 * v1.x; r0.y = p00 * v0.y + p01 * v1.y;
        r0.z = p00 * v0.z + p01 * v1.z; r0.w = p00 * v0.w + p01 * v1.w;
        r1.x = p10 * v0.x + p11 * v1.x; r1.y = p10 * v0.y + p11 * v1.y;
        r1.z = p10 * v0.z + p11 * v1.z; r1.w = p10 * v0.w + p11 * v1.w;
        *reinterpret_cast<float4*>(o0 + c4 * 4) = r0;
        *reinterpret_cast<float4*>(o1 + c4 * 4) = r1;
    }
}

// ---------------------------------------------------------------------------
// Edge aggregation: Rn[s][n][:] = (sum over edges e with row[e]==n of
//   relu(P[s][col[e]][:] + ea[s][e]·W1b)) / cnt[n]
// ---------------------------------------------------------------------------
__global__ __launch_bounds__(256)
void edge_agg_kernel(const float* __restrict__ P, const float* __restrict__ ea,
                     const float* __restrict__ W1, // layer base, rows of 259
                     const int* __restrict__ off, const int* __restrict__ eid,
                     const int* __restrict__ colIdx, const float* __restrict__ cnt,
                     float* __restrict__ Rn)
{
    const int n = blockIdx.x, s = blockIdx.y;
    const int t = threadIdx.x;
    const float w0 = W1[(size_t)t * 259 + 256];
    const float w1 = W1[(size_t)t * 259 + 257];
    const float w2 = W1[(size_t)t * 259 + 258];
    float acc = 0.f;
    const int beg = off[n], end = off[n + 1];
    const float* eab = ea + (size_t)s * EE * 3;
    const float* Pb = P + (size_t)s * NN * HH;
    for (int p = beg; p < end; ++p) {
        int e = eid[p];
        int c = colIdx[e];
        float e0 = eab[(size_t)e * 3 + 0];
        float e1 = eab[(size_t)e * 3 + 1];
        float e2 = eab[(size_t)e * 3 + 2];
        float u = Pb[(size_t)c * HH + t] + e0 * w0 + e1 * w1 + e2 * w2;
        acc += fmaxf(u, 0.f);
    }
    Rn[((size_t)s * NN + n) * HH + t] = acc / cnt[n];
}

// --------------------------- small helper kernels --------------------------
__global__ __launch_bounds__(256)
void enc1_kernel(const float* __restrict__ x, const float* __restrict__ w1,
                 const float* __restrict__ b1, float* __restrict__ t0)
{
    int m = blockIdx.x, j = threadIdx.x;
    float x0 = x[(size_t)m * 3 + 0], x1 = x[(size_t)m * 3 + 1], x2 = x[(size_t)m * 3 + 2];
    float v = fmaf(x0, w1[j * 3 + 0], fmaf(x1, w1[j * 3 + 1], fmaf(x2, w1[j * 3 + 2], b1[j])));
    t0[(size_t)m * HH + j] = fmaxf(v, 0.f);
}

__global__ __launch_bounds__(256)
void deg_kernel(const int* __restrict__ rowIdx, int* __restrict__ deg)
{
    int e = blockIdx.x * 256 + threadIdx.x;
    atomicAdd(&deg[rowIdx[e]], 1);
}

__global__ __launch_bounds__(256)
void cnt_kernel(const int* __restrict__ deg, float* __restrict__ cnt,
                float* __restrict__ bscale)
{
    int n = blockIdx.x * 256 + threadIdx.x;
    int d = deg[n];
    cnt[n] = d > 0 ? (float)d : 1.f;
    float bs = d > 0 ? 1.f : 0.f;
    bscale[n] = bs;
    bscale[NN + n] = bs;
}

__global__ void scan1024(const int* __restrict__ deg, int* __restrict__ off)
{
    __shared__ int tmp[1024];
    int t = threadIdx.x;
    tmp[t] = deg[t];
    __syncthreads();
    for (int d = 1; d < 1024; d <<= 1) {
        int v = 0;
        if (t >= d) v = tmp[t - d];
        __syncthreads();
        if (t >= d) tmp[t] += v;
        __syncthreads();
    }
    off[t + 1] = tmp[t];
    if (t == 0) off[0] = 0;
}

__global__ __launch_bounds__(256)
void csr_scatter(const int* __restrict__ rowIdx, int* __restrict__ cursor,
                 int* __restrict__ eidb)
{
    int e = blockIdx.x * 256 + threadIdx.x;
    int p = atomicAdd(&cursor[rowIdx[e]], 1);
    eidb[p] = e;
}

__global__ __launch_bounds__(256)
void ea_kernel(const float* __restrict__ h, const int* __restrict__ rowIdx,
               const int* __restrict__ colIdx, float* __restrict__ ea)
{
    int idx = blockIdx.x * 256 + threadIdx.x; // [0, SS*EE)
    int e = idx & (EE - 1);
    int s = idx >> 15;
    int r = rowIdx[e], c = colIdx[e];
    const float* hb = h + (size_t)s * NN * HH;
    float* o = ea + (size_t)idx * 3;
    o[0] = hb[(size_t)c * HH + 0] - hb[(size_t)r * HH + 0];
    o[1] = hb[(size_t)c * HH + 1] - hb[(size_t)r * HH + 1];
    o[2] = hb[(size_t)c * HH + 2] - hb[(size_t)r * HH + 2];
}

__global__ __launch_bounds__(256)
void transpose_sn(const float* __restrict__ h, float* __restrict__ ht)
{
    int c = threadIdx.x, n = blockIdx.x, s = blockIdx.y;
    ht[((size_t)n * SS + s) * HH + c] = h[((size_t)s * NN + n) * HH + c];
}

__global__ __launch_bounds__(64)
void final_kernel(const float* __restrict__ o1, const float* __restrict__ w2,
                  const float* __restrict__ b2, float* __restrict__ out)
{
    int n = blockIdx.x, t = threadIdx.x;
    float a0 = 0, a1 = 0, a2 = 0;
#pragma unroll
    for (int r = 0; r < 4; r++) {
        float v = o1[(size_t)n * HH + t + 64 * r];
        a0 = fmaf(v, w2[0 * HH + t + 64 * r], a0);
        a1 = fmaf(v, w2[1 * HH + t + 64 * r], a1);
        a2 = fmaf(v, w2[2 * HH + t + 64 * r], a2);
    }
#pragma unroll
    for (int m = 32; m >= 1; m >>= 1) {
        a0 += __shfl_xor(a0, m);
        a1 += __shfl_xor(a1, m);
        a2 += __shfl_xor(a2, m);
    }
    if (t == 0) {
        out[(size_t)n * 3 + 0] = a0 + b2[0];
        out[(size_t)n * 3 + 1] = a1 + b2[1];
        out[(size_t)n * 3 + 2] = a2 + b2[2];
    }
}

// ---------------------------------------------------------------------------
extern "C" void kernel_launch(void* const* d_in, const int* in_sizes, int n_in,
                              void* d_out, int out_size, void* d_ws, size_t ws_size,
                              hipStream_t stream)
{
    const float* x      = (const float*)d_in[0];
    const int*   eidx   = (const int*)d_in[1];
    const float* fe_w1  = (const float*)d_in[2];
    const float* fe_b1  = (const float*)d_in[3];
    const float* fe_w2  = (const float*)d_in[4];
    const float* fe_b2  = (const float*)d_in[5];
    const float* g_inw  = (const float*)d_in[6];
    const float* g_inb  = (const float*)d_in[7];
    const float* g_outw = (const float*)d_in[8];
    const float* g_outb = (const float*)d_in[9];
    const float* g_m1w  = (const float*)d_in[10];
    const float* g_m1b  = (const float*)d_in[11];
    const float* g_m2w  = (const float*)d_in[12];
    const float* g_m2b  = (const float*)d_in[13];
    const float* g_n1g  = (const float*)d_in[14];
    const float* g_n1b  = (const float*)d_in[15];
    const float* g_n2g  = (const float*)d_in[16];
    const float* g_n2b  = (const float*)d_in[17];
    const float* t_inw  = (const float*)d_in[18];
    const float* t_inb  = (const float*)d_in[19];
    const float* t_outw = (const float*)d_in[20];
    const float* t_outb = (const float*)d_in[21];
    const float* t_l1w  = (const float*)d_in[22];
    const float* t_l1b  = (const float*)d_in[23];
    const float* t_l2w  = (const float*)d_in[24];
    const float* t_l2b  = (const float*)d_in[25];
    const float* t_n1g  = (const float*)d_in[26];
    const float* t_n1b  = (const float*)d_in[27];
    const float* t_n2g  = (const float*)d_in[28];
    const float* t_n2b  = (const float*)d_in[29];
    const float* o_w1   = (const float*)d_in[30];
    const float* o_b1   = (const float*)d_in[31];
    const float* o_w2   = (const float*)d_in[32];
    const float* o_b2   = (const float*)d_in[33];

    const int* rowIdx = eidx;
    const int* colIdx = eidx + EE;

    float* w = (float*)d_ws;
    const size_t F = (size_t)SS * NN * HH; // 524288 floats
    float* h      = w;
    float* hn     = w + F;        // also ht in transformer phase
    float* qkv    = w + 2 * F;    // 3F; also t0 and qkvt
    float* attno  = w + 5 * F;
    float* a      = w + 6 * F;
    float* P      = w + 7 * F;    // also tmp in transformer phase
    float* Rn     = w + 8 * F;
    float* aggn   = w + 9 * F;
    float* ffh    = w + 10 * F;   // 4F
    float* ea     = w + 14 * F;                  // SS*EE*3
    float* o1     = ea + (size_t)SS * EE * 3;    // NN*HH
    float* cnt    = o1 + (size_t)NN * HH;        // NN
    float* bscale = cnt + NN;                    // 2*NN
    int* ib       = (int*)(bscale + 2 * NN);
    int* deg      = ib;                  // NN
    int* off      = ib + NN;             // NN+1
    int* cursor   = ib + 2 * NN + 1;     // NN
    int* eidbuf   = ib + 3 * NN + 1;     // EE

    dim3 b256(256);

    // ---- feature encoder ----
    float* t0 = qkv;
    enc1_kernel<<<dim3(SS * NN), b256, 0, stream>>>(x, fe_w1, fe_b1, t0);
    gemm_xwt32<false, false, false><<<dim3(8, 32), b256, 0, stream>>>(
        t0, HH, fe_w2, HH, fe_b2, nullptr, 0, nullptr, h, HH, HH);

    // ---- graph prep: degrees, CSR, edge attrs ----
    hipMemsetAsync(deg, 0, NN * sizeof(int), stream);
    deg_kernel<<<dim3(EE / 256), b256, 0, stream>>>(rowIdx, deg);
    cnt_kernel<<<dim3(NN / 256), b256, 0, stream>>>(deg, cnt, bscale);
    scan1024<<<dim3(1), dim3(1024), 0, stream>>>(deg, off);
    hipMemcpyAsync(cursor, off, NN * sizeof(int), hipMemcpyDeviceToDevice, stream);
    csr_scatter<<<dim3(EE / 256), b256, 0, stream>>>(rowIdx, cursor, eidbuf);
    ea_kernel<<<dim3(SS * EE / 256), b256, 0, stream>>>(h, rowIdx, colIdx, ea);

    // ---- graph attention + message-passing layers ----
    for (int l = 0; l < LL; l++) {
        ln_kernel<false><<<dim3(SS * NN), b256, 0, stream>>>(
            h, g_n1g + l * HH, g_n1b + l * HH, nullptr, hn);
        gemm_xwt32<false, false, false><<<dim3(24, 32), b256, 0, stream>>>(
            hn, HH, g_inw + (size_t)l * 3 * HH * HH, HH, g_inb + l * 3 * HH,
            nullptr, 0, nullptr, qkv, 3 * HH, HH);
        attn_graph_kernel<<<dim3(32, NHEAD, SS), b256, 0, stream>>>(qkv, attno);
        gemm_xwt32<false, true, false><<<dim3(8, 32), b256, 0, stream>>>(
            attno, HH, g_outw + (size_t)l * HH * HH, HH, g_outb + l * HH,
            h, HH, nullptr, a, HH, HH);
        // P = a @ W1a^T + b1   (W1 rows are length 259: 256 for a, 3 for ea)
        gemm_xwt32<false, false, false><<<dim3(8, 32), b256, 0, stream>>>(
            a, HH, g_m1w + (size_t)l * HH * 259, 259, g_m1b + l * HH,
            nullptr, 0, nullptr, P, HH, HH);
        edge_agg_kernel<<<dim3(NN, SS), b256, 0, stream>>>(
            P, ea, g_m1w + (size_t)l * HH * 259, off, eidbuf, colIdx, cnt, Rn);
        gemm_xwt32<false, false, true><<<dim3(8, 32), b256, 0, stream>>>(
            Rn, HH, g_m2w + (size_t)l * HH * HH, HH, g_m2b + l * HH,
            nullptr, 0, bscale, aggn, HH, HH);
        ln_kernel<true><<<dim3(SS * NN), b256, 0, stream>>>(
            aggn, g_n2g + l * HH, g_n2b + l * HH, h, h);
    }

    // ---- transpose to [n][s][H] ----
    float* ht = hn;
    transpose_sn<<<dim3(NN, SS), b256, 0, stream>>>(h, ht);

    // ---- transformer layers over T=S=2 ----
    float* tmp = P;
    for (int l = 0; l < LL; l++) {
        gemm_xwt32<false, false, false><<<dim3(24, 32), b256, 0, stream>>>(
            ht, HH, t_inw + (size_t)l * 3 * HH * HH, HH, t_inb + l * 3 * HH,
            nullptr, 0, nullptr, qkv, 3 * HH, HH);
        attn_t2_kernel<<<dim3(NN * NHEAD / 256), b256, 0, stream>>>(qkv, attno);
        gemm_xwt32<false, true, false><<<dim3(8, 32), b256, 0, stream>>>(
            attno, HH, t_outw + (size_t)l * HH * HH, HH, t_outb + l * HH,
            ht, HH, nullptr, tmp, HH, HH);
        ln_kernel<false><<<dim3(SS * NN), b256, 0, stream>>>(
            tmp, t_n1g + l * HH, t_n1b + l * HH, nullptr, ht);
        gemm_xwt32<true, false, false><<<dim3(32, 32), b256, 0, stream>>>(
            ht, HH, t_l1w + (size_t)l * 4 * HH * HH, HH, t_l1b + l * 4 * HH,
            nullptr, 0, nullptr, ffh, 4 * HH, HH);
        gemm_xwt32<false, true, false><<<dim3(8, 32), b256, 0, stream>>>(
            ffh, 4 * HH, t_l2w + (size_t)l * HH * 4 * HH, 4 * HH, t_l2b + l * HH,
            ht, HH, nullptr, tmp, HH, 4 * HH);
        ln_kernel<false><<<dim3(SS * NN), b256, 0, stream>>>(
            tmp, t_n2g + l * HH, t_n2b + l * HH, nullptr, ht);
    }

    // ---- output head: last = ht[:, s=1, :] ----
    gemm_xwt32<true, false, false><<<dim3(8, 16), b256, 0, stream>>>(
        ht + HH, 2 * HH, o_w1, HH, o_b1, nullptr, 0, nullptr, o1, HH, HH);
    final_kernel<<<dim3(NN), dim3(64), 0, stream>>>(o1, o_w2, o_b2, (float*)d_out);
}